// Round 9
// baseline (224.524 us; speedup 1.0000x reference)
//
#include <hip/hip_runtime.h>

#define G_ 1024
#define DIN_ 3072
#define B_ 8192
#define TB 2          // rows staged per block (24 KiB LDS; 24 KiB dirty out-tile)
#define TPB 512
#define GPT 2         // consecutive groups per thread

// ---------------------------------------------------------------------------
// Fused single kernel (round-5 structure; round-9 change: TB 4->2 + 4 blk/CU).
// out[b,g,m] = K + cx0*x0 + cx1*x1 + cx2*x2 + cq01*x0x1 + cq02*x0x2 + cq12*x1x2
// where x_i = x[b, conn[g,i]]; the 7 coeffs per (g,m) fold the soft-gate,
// the 6 Fredkin permutations, and the softmax weights.
//
// Dirty-footprint budget (the R6/R7 lesson): per XCD-L2 (4 MiB) the
// co-resident dirty output tiles must fit:
//   32 CU x 4 blk x (TB=2 rows x 12 KiB) = 3 MiB < 4 MiB  -> no write amp.
// (R6's 3 blk x 48 KiB = 4.5 MiB gave WRITE 98->151 MB and +34% time.)
//
// Schedule per block:
//   1) issue 3x global_load_lds (2 rows -> 24 KiB LDS, linear dest)
//   2) recompute 2 groups' coefficients in registers (covers stage latency;
//      4 decorrelated blocks/CU cover each other's barriers)
//   3) __syncthreads
//   4) 2 rows x { 6 LDS gathers, 42 FMA, 24 B contiguous store }
// 512 thr, VGPR ~48 <= 64, __launch_bounds__(512,8) -> 4 blocks/CU, 32 waves.
// ---------------------------------------------------------------------------
__global__ __launch_bounds__(TPB, 8) void fredkin_fused_kernel(
    const float* __restrict__ x, const int* __restrict__ conn,
    const float* __restrict__ sel, const float* __restrict__ wg,
    float* __restrict__ out)
{
    __shared__ float xs[TB * DIN_];   // 24 KiB
    const int t = threadIdx.x;
    const int row0 = blockIdx.x * TB;

    // ---- phase 1: issue direct-to-LDS stage (3 x 16 B per thread) ----
    const float4* xv = (const float4*)(x + (size_t)row0 * DIN_);
    float4* sv = (float4*)xs;
#pragma unroll
    for (int i = 0; i < (TB * DIN_ / 4) / TPB; ++i)   // 3 iters
        __builtin_amdgcn_global_load_lds(
            (const __attribute__((address_space(1))) void*)(xv + t + i * TPB),
            (__attribute__((address_space(3))) void*)(sv + t + i * TPB),
            16, 0, 0);

    // ---- phase 2: coefficient recompute for GPT consecutive groups ----
    int   cc[GPT][3];
    float CF[GPT][3][7];   // per m: K, cx0, cx1, cx2, cq01, cq02, cq12
#pragma unroll
    for (int gi = 0; gi < GPT; ++gi) {
        const int g = t * GPT + gi;

        float u[3], v[3];
#pragma unroll
        for (int i = 0; i < 3; ++i) {
            cc[gi][i] = conn[g * 3 + i];
            float s = sel[g * 3 + i];
            float C = s / (1.0f + fabsf(s));
            float a = fabsf(C);
            u[i] = 1.0f - a;
            v[i] = 0.5f * (C + a);
        }

        // softmax over 6 permutation weights
        float w[6];
        float mx = -1e30f;
#pragma unroll
        for (int p = 0; p < 6; ++p) mx = fmaxf(mx, wg[g * 6 + p]);
        float sum = 0.0f;
#pragma unroll
        for (int p = 0; p < 6; ++p) { w[p] = __expf(wg[g * 6 + p] - mx); sum += w[p]; }
        float inv = 1.0f / sum;
#pragma unroll
        for (int p = 0; p < 6; ++p) w[p] *= inv;

        // itertools.permutations(range(3)); signals:
        // m0 = a ; m1 = c + ab - ac ; m2 = b - ab + ac  (a,b,c = permuted gated)
        const int P[6][3] = {{0,1,2},{0,2,1},{1,0,2},{1,2,0},{2,0,1},{2,1,0}};
        float L[3][3] = {{0.f,0.f,0.f},{0.f,0.f,0.f},{0.f,0.f,0.f}};
        float Q[3][3] = {{0.f,0.f,0.f},{0.f,0.f,0.f},{0.f,0.f,0.f}};
#pragma unroll
        for (int p = 0; p < 6; ++p) {
            int i0 = P[p][0], i1 = P[p][1], i2 = P[p][2];
            float wp = w[p];
            int p01 = i0 + i1 - 1;   // pair idx (i,j)->i+j-1, i<j
            int p02 = i0 + i2 - 1;
            L[0][i0] += wp;
            L[1][i2] += wp; Q[1][p01] += wp; Q[1][p02] -= wp;
            L[2][i1] += wp; Q[2][p01] -= wp; Q[2][p02] += wp;
        }

        // substitute gated_i = u_i*x_i + v_i -> x-space coefficients
#pragma unroll
        for (int m = 0; m < 3; ++m) {
            CF[gi][m][0] = L[m][0]*v[0] + L[m][1]*v[1] + L[m][2]*v[2]
                         + Q[m][0]*v[0]*v[1] + Q[m][1]*v[0]*v[2] + Q[m][2]*v[1]*v[2];
            CF[gi][m][1] = u[0]*(L[m][0] + Q[m][0]*v[1] + Q[m][1]*v[2]);
            CF[gi][m][2] = u[1]*(L[m][1] + Q[m][0]*v[0] + Q[m][2]*v[2]);
            CF[gi][m][3] = u[2]*(L[m][2] + Q[m][1]*v[0] + Q[m][2]*v[1]);
            CF[gi][m][4] = Q[m][0]*u[0]*u[1];
            CF[gi][m][5] = Q[m][1]*u[0]*u[2];
            CF[gi][m][6] = Q[m][2]*u[1]*u[2];
        }
    }

    // ---- phase 3: barrier (stage landed under phase 2 / sibling blocks) ----
    __syncthreads();

    // ---- phase 4: evaluate TB rows ----
#pragma unroll
    for (int r = 0; r < TB; ++r) {
        const float* xb = xs + r * DIN_;
        // all 6 gathers independent, issued together
        float gx[GPT][3];
#pragma unroll
        for (int gi = 0; gi < GPT; ++gi) {
            gx[gi][0] = xb[cc[gi][0]];
            gx[gi][1] = xb[cc[gi][1]];
            gx[gi][2] = xb[cc[gi][2]];
        }
        float o[GPT * 3];
#pragma unroll
        for (int gi = 0; gi < GPT; ++gi) {
            const float x0 = gx[gi][0], x1 = gx[gi][1], x2 = gx[gi][2];
            const float p01 = x0 * x1, p02 = x0 * x2, p12 = x1 * x2;
#pragma unroll
            for (int m = 0; m < 3; ++m) {
                o[gi * 3 + m] = CF[gi][m][0]
                              + CF[gi][m][1]*x0 + CF[gi][m][2]*x1 + CF[gi][m][3]*x2
                              + CF[gi][m][4]*p01 + CF[gi][m][5]*p02 + CF[gi][m][6]*p12;
            }
        }
        // 24 B contiguous per lane -> wave writes 1536 B contiguous
        float2* op = (float2*)(out + (size_t)(row0 + r) * (3 * G_) + (size_t)t * (3 * GPT));
        op[0] = make_float2(o[0], o[1]);
        op[1] = make_float2(o[2], o[3]);
        op[2] = make_float2(o[4], o[5]);
    }
}

extern "C" void kernel_launch(void* const* d_in, const int* in_sizes, int n_in,
                              void* d_out, int out_size, void* d_ws, size_t ws_size,
                              hipStream_t stream) {
    const float* x    = (const float*)d_in[0];
    const int*   conn = (const int*)d_in[1];
    const float* sel  = (const float*)d_in[2];
    const float* wg   = (const float*)d_in[3];
    float* out = (float*)d_out;

    hipLaunchKernelGGL(fredkin_fused_kernel, dim3(B_ / TB), dim3(TPB), 0, stream,
                       x, conn, sel, wg, out);
}

// Round 10
// 114.501 us; speedup vs baseline: 1.9609x; 1.9609x over previous
//
#include <hip/hip_runtime.h>

#define G_ 1024
#define DIN_ 3072
#define B_ 8192
#define TBR 2         // rows per block (24 KiB L1 working set)
#define TPB 512

// ---------------------------------------------------------------------------
// Kernel 1: per-group parameter precompute (verified in R2/R1).
// out[b,g,m] = K + cx0*x0 + cx1*x1 + cx2*x2 + cq01*x0x1 + cq02*x0x2 + cq12*x1x2
// Packed record per group: 32 floats (128 B):
//   [0..2] conn (int bits), [3] pad
//   [4+8m .. 10+8m] K, cx0, cx1, cx2, cq01, cq02, cq12 (m=0..2), [+7] pad
// ---------------------------------------------------------------------------
__global__ __launch_bounds__(256) void fredkin_coef_kernel(
    const int* __restrict__ conn, const float* __restrict__ sel,
    const float* __restrict__ wg, float* __restrict__ cw)
{
    int g = blockIdx.x * blockDim.x + threadIdx.x;
    if (g >= G_) return;

    float u[3], v[3];
#pragma unroll
    for (int i = 0; i < 3; ++i) {
        float s = sel[g * 3 + i];
        float C = s / (1.0f + fabsf(s));
        float a = fabsf(C);
        u[i] = 1.0f - a;          // multiplier on x
        v[i] = 0.5f * (C + a);    // additive bias
    }

    float w[6];
    float mx = -1e30f;
#pragma unroll
    for (int p = 0; p < 6; ++p) mx = fmaxf(mx, wg[g * 6 + p]);
    float sum = 0.0f;
#pragma unroll
    for (int p = 0; p < 6; ++p) { w[p] = expf(wg[g * 6 + p] - mx); sum += w[p]; }
    float inv = 1.0f / sum;
#pragma unroll
    for (int p = 0; p < 6; ++p) w[p] *= inv;

    // itertools.permutations(range(3)); signals:
    // m0 = a ; m1 = c + ab - ac ; m2 = b - ab + ac  (a,b,c = permuted gated)
    const int P[6][3] = {{0,1,2},{0,2,1},{1,0,2},{1,2,0},{2,0,1},{2,1,0}};
    float L[3][3] = {{0.f,0.f,0.f},{0.f,0.f,0.f},{0.f,0.f,0.f}};
    float Q[3][3] = {{0.f,0.f,0.f},{0.f,0.f,0.f},{0.f,0.f,0.f}};
#pragma unroll
    for (int p = 0; p < 6; ++p) {
        int i0 = P[p][0], i1 = P[p][1], i2 = P[p][2];
        float wp = w[p];
        int p01 = i0 + i1 - 1;   // pair idx (i,j)->i+j-1, i<j
        int p02 = i0 + i2 - 1;
        L[0][i0] += wp;
        L[1][i2] += wp; Q[1][p01] += wp; Q[1][p02] -= wp;
        L[2][i1] += wp; Q[2][p01] -= wp; Q[2][p02] += wp;
    }

    float* o = cw + (size_t)g * 32;
    int* oi = (int*)o;
    oi[0] = conn[g * 3 + 0];
    oi[1] = conn[g * 3 + 1];
    oi[2] = conn[g * 3 + 2];
    oi[3] = 0;

    // substitute gated_i = u_i*x_i + v_i -> x-space coefficients
#pragma unroll
    for (int m = 0; m < 3; ++m) {
        float K = L[m][0]*v[0] + L[m][1]*v[1] + L[m][2]*v[2]
                + Q[m][0]*v[0]*v[1] + Q[m][1]*v[0]*v[2] + Q[m][2]*v[1]*v[2];
        float cx0 = u[0]*(L[m][0] + Q[m][0]*v[1] + Q[m][1]*v[2]);
        float cx1 = u[1]*(L[m][1] + Q[m][0]*v[0] + Q[m][2]*v[2]);
        float cx2 = u[2]*(L[m][2] + Q[m][1]*v[0] + Q[m][2]*v[1]);
        float* om = o + 4 + m * 8;
        om[0]=K; om[1]=cx0; om[2]=cx1; om[3]=cx2;
        om[4]=Q[m][0]*u[0]*u[1]; om[5]=Q[m][1]*u[0]*u[2]; om[6]=Q[m][2]*u[1]*u[2];
        om[7]=0.f;
    }
}

// ---------------------------------------------------------------------------
// Kernel 2: barrier-free, LDS-free evaluation.
// Block = 512 threads owns 2 rows; thread t owns groups {2t, 2t+1}.
// - params: 14 contiguous dwordx4 from the packed table (L2/L3-resident)
// - gathers: scalar global loads; each 64 B row-line is hit ~16x within the
//   block -> L1 serves the reuse, first touch self-fetches (rows span only
//   3 HBM pages, so random-order line fills lose ~nothing).
// - NO __syncthreads: all waves fully decorrelated -> reads/gathers/writes
//   continuously mixed on the HBM link (the R5 limiter was barrier-bursty
//   demand at 2 barrier-groups/CU).
// Dirty-footprint check (R6/R9 lesson): 32 CU x 3 blk x 24 KiB = 2.25 MiB
// < 4 MiB XCD-L2 -> no write amplification expected.
// ---------------------------------------------------------------------------
__global__ __launch_bounds__(TPB, 6) void fredkin_eval_kernel(
    const float* __restrict__ x, const float* __restrict__ cw,
    float* __restrict__ out)
{
    const int t = threadIdx.x;
    const int row0 = blockIdx.x * TBR;

    // params for groups 2t, 2t+1 (256 B contiguous per thread)
    const float4* cf = (const float4*)(cw + (size_t)(2 * t) * 32);
    const int4   cA  = ((const int4*)cf)[0];
    const float4 aA0 = cf[1], qA0 = cf[2];
    const float4 aA1 = cf[3], qA1 = cf[4];
    const float4 aA2 = cf[5], qA2 = cf[6];
    const int4   cB  = ((const int4*)cf)[8];
    const float4 aB0 = cf[9],  qB0 = cf[10];
    const float4 aB1 = cf[11], qB1 = cf[12];
    const float4 aB2 = cf[13], qB2 = cf[14];

#pragma unroll
    for (int r = 0; r < TBR; ++r) {
        const float* xr = x + (size_t)(row0 + r) * DIN_;
        // 6 independent gathers (L1 after first touch)
        const float xa0 = xr[cA.x], xa1 = xr[cA.y], xa2 = xr[cA.z];
        const float xb0 = xr[cB.x], xb1 = xr[cB.y], xb2 = xr[cB.z];

        const float pa01 = xa0 * xa1, pa02 = xa0 * xa2, pa12 = xa1 * xa2;
        const float pb01 = xb0 * xb1, pb02 = xb0 * xb2, pb12 = xb1 * xb2;

        float oA0 = aA0.x + aA0.y*xa0 + aA0.z*xa1 + aA0.w*xa2 + qA0.x*pa01 + qA0.y*pa02 + qA0.z*pa12;
        float oA1 = aA1.x + aA1.y*xa0 + aA1.z*xa1 + aA1.w*xa2 + qA1.x*pa01 + qA1.y*pa02 + qA1.z*pa12;
        float oA2 = aA2.x + aA2.y*xa0 + aA2.z*xa1 + aA2.w*xa2 + qA2.x*pa01 + qA2.y*pa02 + qA2.z*pa12;
        float oB0 = aB0.x + aB0.y*xb0 + aB0.z*xb1 + aB0.w*xb2 + qB0.x*pb01 + qB0.y*pb02 + qB0.z*pb12;
        float oB1 = aB1.x + aB1.y*xb0 + aB1.z*xb1 + aB1.w*xb2 + qB1.x*pb01 + qB1.y*pb02 + qB1.z*pb12;
        float oB2 = aB2.x + aB2.y*xb0 + aB2.z*xb1 + aB2.w*xb2 + qB2.x*pb01 + qB2.y*pb02 + qB2.z*pb12;

        // 24 B contiguous per lane -> wave covers 1536 B contiguous
        float2* op = (float2*)(out + (size_t)(row0 + r) * (3 * G_) + (size_t)t * 6);
        op[0] = make_float2(oA0, oA1);
        op[1] = make_float2(oA2, oB0);
        op[2] = make_float2(oB1, oB2);
    }
}

extern "C" void kernel_launch(void* const* d_in, const int* in_sizes, int n_in,
                              void* d_out, int out_size, void* d_ws, size_t ws_size,
                              hipStream_t stream) {
    const float* x    = (const float*)d_in[0];
    const int*   conn = (const int*)d_in[1];
    const float* sel  = (const float*)d_in[2];
    const float* wg   = (const float*)d_in[3];
    float* out = (float*)d_out;
    float* cw  = (float*)d_ws;   // G_*32 floats = 128 KiB

    hipLaunchKernelGGL(fredkin_coef_kernel, dim3(G_ / 256), dim3(256), 0, stream,
                       conn, sel, wg, cw);
    hipLaunchKernelGGL(fredkin_eval_kernel, dim3(B_ / TBR), dim3(TPB), 0, stream,
                       x, cw, out);
}

// Round 11
// 35.769 us; speedup vs baseline: 6.2771x; 3.2011x over previous
//
#include <hip/hip_runtime.h>

#define G_ 1024
#define DIN_ 3072
#define B_ 8192
#define TPB 512
#define UNITS 8            // 2-row units per block -> 16 rows/block
#define NBUF 3             // LDS ring depth (stage-ahead 2)
#define UFLOAT (2 * DIN_)  // floats per unit = 6144 (24 KiB)

// LDS byte offset of a generic pointer that lives in LDS
__device__ __forceinline__ unsigned lds_off(const float* p) {
    return (unsigned)(unsigned long long)(__attribute__((address_space(3))) const float*)p;
}

// ---------------------------------------------------------------------------
// Counted-vmcnt ring pipeline (T3/T4 applied to a streaming gather kernel).
// out[b,g,m] = K + cx0*x0 + cx1*x1 + cx2*x2 + cq01*x0x1 + cq02*x0x2 + cq12*x1x2
// coeffs fold soft-gate + 6 Fredkin perms + softmax; computed once per block.
//
// Per iteration u (unit = 2 rows, buffer u%3):
//   s_waitcnt vmcnt(N)   N = 3 (u=0) / 6 (u=7) / 9 else  -- NEVER 0:
//       guarantees stage(u) landed while stage(u+1),(u+2) + recent stores fly
//   s_barrier            (raw -- no compiler vmcnt(0) drain)
//   STAGE(u+2)           3x global_load_lds dwordx4 into buf[(u+2)%3]
//   m0 = -1; 12x asm ds_read_b32 gathers; lgkmcnt(0); sched_barrier
//   84 FMA; 6x float2 stores (paced by the counted vmcnt -> no store bursts)
// Ring safety: stage(u+2) overwrites buf last gathered at iter u-1; gathers
// complete (lgkmcnt 0) before each wave reaches barrier(u) -> WAR safe.
// vmcnt FIFO audit (per wave, 3 stage + 6 store per iter, cross-iter order
// fixed by barriers): newer-than-stage(u) >= {stage(u+1):3, stores(u-1):6}=9.
// LDS 72 KiB -> 2 blocks/CU; grid 512 = exactly 2/CU, persistent.
// ---------------------------------------------------------------------------
__global__ __launch_bounds__(TPB, 4) void fredkin_pipe_kernel(
    const float* __restrict__ x, const int* __restrict__ conn,
    const float* __restrict__ sel, const float* __restrict__ wg,
    float* __restrict__ out)
{
    __shared__ float xs[NBUF * UFLOAT];   // 72 KiB ring
    const int t = threadIdx.x;
    const int row0 = blockIdx.x * (2 * UNITS);

    // stage unit s (2 rows) into buf s%NBUF: 3 x 16 B per thread, linear dest
    auto STAGE = [&](int s) {
        const float4* src = (const float4*)(x + (size_t)(row0 + 2 * s) * DIN_);
        float4* dst = (float4*)(xs + (s % NBUF) * UFLOAT);
#pragma unroll
        for (int i = 0; i < (UFLOAT / 4) / TPB; ++i)   // 3 iters
            __builtin_amdgcn_global_load_lds(
                (const __attribute__((address_space(1))) void*)(src + t + i * TPB),
                (__attribute__((address_space(3))) void*)(dst + t + i * TPB),
                16, 0, 0);
    };

    STAGE(0);
    asm volatile("" ::: "memory");   // pin issue order (vmcnt FIFO accounting)
    STAGE(1);
    asm volatile("" ::: "memory");

    // ---- coefficient compute for groups 2t, 2t+1 (covers stage flight) ----
    int   cc[2][3];
    float CF[2][3][7];   // per m: K, cx0, cx1, cx2, cq01, cq02, cq12
#pragma unroll
    for (int gi = 0; gi < 2; ++gi) {
        const int g = 2 * t + gi;
        float u_[3], v_[3];
#pragma unroll
        for (int i = 0; i < 3; ++i) {
            cc[gi][i] = conn[g * 3 + i];
            float s = sel[g * 3 + i];
            float C = s / (1.0f + fabsf(s));
            float a = fabsf(C);
            u_[i] = 1.0f - a;
            v_[i] = 0.5f * (C + a);
        }
        float w[6];
        float mx = -1e30f;
#pragma unroll
        for (int p = 0; p < 6; ++p) mx = fmaxf(mx, wg[g * 6 + p]);
        float sum = 0.0f;
#pragma unroll
        for (int p = 0; p < 6; ++p) { w[p] = __expf(wg[g * 6 + p] - mx); sum += w[p]; }
        float inv = 1.0f / sum;
#pragma unroll
        for (int p = 0; p < 6; ++p) w[p] *= inv;

        // itertools.permutations(range(3)); signals:
        // m0 = a ; m1 = c + ab - ac ; m2 = b - ab + ac  (a,b,c = permuted gated)
        const int P[6][3] = {{0,1,2},{0,2,1},{1,0,2},{1,2,0},{2,0,1},{2,1,0}};
        float L[3][3] = {{0.f,0.f,0.f},{0.f,0.f,0.f},{0.f,0.f,0.f}};
        float Q[3][3] = {{0.f,0.f,0.f},{0.f,0.f,0.f},{0.f,0.f,0.f}};
#pragma unroll
        for (int p = 0; p < 6; ++p) {
            int i0 = P[p][0], i1 = P[p][1], i2 = P[p][2];
            float wp = w[p];
            int p01 = i0 + i1 - 1;   // pair idx (i,j)->i+j-1, i<j
            int p02 = i0 + i2 - 1;
            L[0][i0] += wp;
            L[1][i2] += wp; Q[1][p01] += wp; Q[1][p02] -= wp;
            L[2][i1] += wp; Q[2][p01] -= wp; Q[2][p02] += wp;
        }
#pragma unroll
        for (int m = 0; m < 3; ++m) {
            CF[gi][m][0] = L[m][0]*v_[0] + L[m][1]*v_[1] + L[m][2]*v_[2]
                         + Q[m][0]*v_[0]*v_[1] + Q[m][1]*v_[0]*v_[2] + Q[m][2]*v_[1]*v_[2];
            CF[gi][m][1] = u_[0]*(L[m][0] + Q[m][0]*v_[1] + Q[m][1]*v_[2]);
            CF[gi][m][2] = u_[1]*(L[m][1] + Q[m][0]*v_[0] + Q[m][2]*v_[2]);
            CF[gi][m][3] = u_[2]*(L[m][2] + Q[m][1]*v_[0] + Q[m][2]*v_[1]);
            CF[gi][m][4] = Q[m][0]*u_[0]*u_[1];
            CF[gi][m][5] = Q[m][1]*u_[0]*u_[2];
            CF[gi][m][6] = Q[m][2]*u_[1]*u_[2];
        }
    }

    const unsigned xbase = lds_off(xs);

    // ---- main pipeline ----
#pragma unroll
    for (int u = 0; u < UNITS; ++u) {
        // counted wait: stage(u) complete; stage(u+1),(u+2)+stores stay in flight
        if (u == 0)              asm volatile("s_waitcnt vmcnt(3)" ::: "memory");
        else if (u == UNITS - 1) asm volatile("s_waitcnt vmcnt(6)" ::: "memory");
        else                     asm volatile("s_waitcnt vmcnt(9)" ::: "memory");
        __builtin_amdgcn_s_barrier();   // raw: no drain

        if (u + 2 < UNITS) STAGE(u + 2);
        asm volatile("" ::: "memory");

        // gload_lds codegen overwrites m0 (LDS dest base); DS ops use m0 as
        // the LDS limit -> restore before asm gathers.
        asm volatile("s_mov_b32 m0, -1" ::: "memory");

        const unsigned bb = xbase + (unsigned)((u % NBUF) * UFLOAT) * 4u;
        float gv[2][2][3];   // [lr][gi][k], all indices compile-time
#pragma unroll
        for (int lr = 0; lr < 2; ++lr)
#pragma unroll
            for (int gi = 0; gi < 2; ++gi)
#pragma unroll
                for (int k = 0; k < 3; ++k) {
                    unsigned addr = bb + (unsigned)(lr * DIN_ + cc[gi][k]) * 4u;
                    asm volatile("ds_read_b32 %0, %1"
                                 : "=v"(gv[lr][gi][k]) : "v"(addr));
                }
        asm volatile("s_waitcnt lgkmcnt(0)" ::: "memory");
        __builtin_amdgcn_sched_barrier(0);

#pragma unroll
        for (int lr = 0; lr < 2; ++lr) {
            float o[6];
#pragma unroll
            for (int gi = 0; gi < 2; ++gi) {
                const float x0 = gv[lr][gi][0], x1 = gv[lr][gi][1], x2 = gv[lr][gi][2];
                const float p01 = x0 * x1, p02 = x0 * x2, p12 = x1 * x2;
#pragma unroll
                for (int m = 0; m < 3; ++m)
                    o[gi * 3 + m] = CF[gi][m][0]
                                  + CF[gi][m][1]*x0 + CF[gi][m][2]*x1 + CF[gi][m][3]*x2
                                  + CF[gi][m][4]*p01 + CF[gi][m][5]*p02 + CF[gi][m][6]*p12;
            }
            // 24 B contiguous per lane (3 x dwordx2), 6 stores per unit
            float2* op = (float2*)(out + (size_t)(row0 + 2*u + lr) * DIN_ + (size_t)t * 6);
            op[0] = make_float2(o[0], o[1]);
            op[1] = make_float2(o[2], o[3]);
            op[2] = make_float2(o[4], o[5]);
        }
    }
}

extern "C" void kernel_launch(void* const* d_in, const int* in_sizes, int n_in,
                              void* d_out, int out_size, void* d_ws, size_t ws_size,
                              hipStream_t stream) {
    const float* x    = (const float*)d_in[0];
    const int*   conn = (const int*)d_in[1];
    const float* sel  = (const float*)d_in[2];
    const float* wg   = (const float*)d_in[3];
    float* out = (float*)d_out;

    hipLaunchKernelGGL(fredkin_pipe_kernel, dim3(B_ / (2 * UNITS)), dim3(TPB), 0, stream,
                       x, conn, sel, wg, out);
}